// Round 12
// baseline (942.769 us; speedup 1.0000x reference)
//
#include <hip/hip_runtime.h>

#define NN 100000
#define NE 1600000
#define EPS_BN 1e-5f
#define NSHADOW 64
#define STATS_SC_OFF (NSHADOW*512)
#define STATS_SH_OFF (NSHADOW*512 + 256)

typedef unsigned short ushort_t;
typedef unsigned long long u64;
typedef _Float16 f16;
typedef short v8s __attribute__((ext_vector_type(8)));     // 8 bf16 (4 VGPR)
typedef ushort_t us8 __attribute__((ext_vector_type(8)));  // 8 bf16 as ushort
typedef float v4f __attribute__((ext_vector_type(4)));     // 4 fp32 acc
typedef f16 f16x2 __attribute__((ext_vector_type(2)));
typedef f16 f16x4 __attribute__((ext_vector_type(4)));

__device__ __forceinline__ float lk(float x){ return x >= 0.f ? x : 0.1f*x; }

__device__ __forceinline__ ushort_t f2bf(float x){
  unsigned u = __float_as_uint(x);
  unsigned r = (u + 0x7fffu + ((u >> 16) & 1u)) >> 16;
  return (ushort_t)r;
}
__device__ __forceinline__ float bf2f(ushort_t h){
  return __uint_as_float(((unsigned)h) << 16);
}
__device__ __forceinline__ void split2(float x, ushort_t& hi, ushort_t& lo){
  hi = f2bf(x);
  lo = f2bf(x - bf2f(hi));
}

// async 16B global->LDS (lds dst is wave-uniform base; HW adds lane*16)
__device__ __forceinline__ void gload16(const ushort_t* g, ushort_t* l){
  __builtin_amdgcn_global_load_lds((const __attribute__((address_space(1))) void*)g,
                                   (__attribute__((address_space(3))) void*)l, 16, 0, 0);
}

// ---------------- degree+count histogram: ONE packed u64 atomic per edge ----------------
__global__ void zero_acc(u64* __restrict__ acc, int n){
  int i = blockIdx.x*256 + threadIdx.x;
  if (i < n) acc[i] = 0ull;
}

__global__ void edge_hist(const int* __restrict__ dst, const float* __restrict__ ew,
                          u64* __restrict__ acc, ushort_t* __restrict__ rank, int e){
  int i = blockIdx.x*256 + threadIdx.x;
  if (i < e){
    int d = dst[i];
    unsigned fx = (unsigned)(ew[i] * 67108864.0f + 0.5f);   // 2^26 fixed point
    u64 old = atomicAdd(&acc[d], (1ull << 40) | (u64)fx);
    rank[i] = (ushort_t)(old >> 40);                        // in-bucket rank
  }
}

__global__ void finalize_acc(const u64* __restrict__ acc, float* __restrict__ dinv,
                             int* __restrict__ cnt, int n){
  int i = blockIdx.x*256 + threadIdx.x;
  if (i < n){
    u64 v = acc[i];
    cnt[i] = (int)(v >> 40);
    double w = (double)(v & 0xFFFFFFFFFFull) * (1.0/67108864.0);
    dinv[i] = rsqrtf((float)(1.0 + w));   // +1 self loop
  }
}

// ---------------- exclusive scan (3-kernel) ----------------
__global__ __launch_bounds__(1024) void scan_block(const int* __restrict__ in, int* __restrict__ out,
                                                   int* __restrict__ bsum, int n){
  __shared__ int s[1024];
  int t = threadIdx.x;
  int i = blockIdx.x*1024 + t;
  int v = (i < n) ? in[i] : 0;
  s[t] = v; __syncthreads();
  for (int off = 1; off < 1024; off <<= 1){
    int x = (t >= off) ? s[t-off] : 0;
    __syncthreads();
    s[t] += x;
    __syncthreads();
  }
  if (i < n) out[i] = s[t] - v;
  if (t == 1023) bsum[blockIdx.x] = s[1023];
}

__global__ void scan_small(int* __restrict__ bsum, int nb){
  __shared__ int s[128];
  int t = threadIdx.x;
  int v = (t < nb) ? bsum[t] : 0;
  s[t] = v; __syncthreads();
  for (int off = 1; off < 128; off <<= 1){
    int x = (t >= off) ? s[t-off] : 0;
    __syncthreads();
    s[t] += x;
    __syncthreads();
  }
  if (t < nb) bsum[t] = s[t] - v;
}

__global__ __launch_bounds__(1024) void scan_add(int* __restrict__ rp,
                                                 const int* __restrict__ bsum, int n, int etot){
  int i = blockIdx.x*1024 + threadIdx.x;
  if (i < n) rp[i] += bsum[blockIdx.x];
  if (i == 0) rp[n] = etot;
}

// ---------------- CSR fill: atomic-free (pos = rp[d] + rank), one 8B scatter/edge ----------------
__global__ void fill_csr_k(const int* __restrict__ src, const int* __restrict__ dst,
                           const float* __restrict__ ew, const float* __restrict__ dinv,
                           const int* __restrict__ rp, const ushort_t* __restrict__ rank,
                           int2* __restrict__ csr_sw, int e){
  int i = blockIdx.x*256 + threadIdx.x;
  if (i >= e) return;
  int s = src[i], d = dst[i];
  int pos = rp[d] + (int)rank[i];
  float w = dinv[s] * ew[i] * dinv[d];
  csr_sw[pos] = make_int2(s, __float_as_int(w));
}

// ---------------- x fp32 -> fp16 convert ----------------
__global__ void cvt_x(const float* __restrict__ in, f16* __restrict__ out, int n4){
  int i = blockIdx.x*256 + threadIdx.x;
  if (i >= n4) return;
  float4 v = ((const float4*)in)[i];
  f16x4 h = (f16x4){(f16)v.x, (f16)v.y, (f16)v.z, (f16)v.w};
  ((f16x4*)out)[i] = h;
}

// ---------------- SpMM (256 ch total), channel-split into 2 passes of 128 ch ----------------
// 4 nodes per wave, continuous gather pipeline; BN stats fused (per-pass 128 ch).
// Settled at its access-pattern floor (~129 us) in r2/r6 — do not touch.
__global__ __launch_bounds__(256) void spmm16(const f16* __restrict__ h,
    const int* __restrict__ rp, const int2* __restrict__ csr_sw,
    const float* __restrict__ dinv, const float* __restrict__ bias,
    float* __restrict__ out, float* __restrict__ stats, int n){
  const int pass = blockIdx.y;                 // 0: ch 0..127 ; 1: ch 128..255
  int nbase = __builtin_amdgcn_readfirstlane(blockIdx.x*16 + (threadIdx.x >> 6)*4);
  if (nbase >= n) return;
  int lane = threadIdx.x & 63;
  const f16* hb = h + pass*128 + lane*2;       // 2 fp16 channels per lane

  int P[5];
#pragma unroll
  for (int i = 0; i < 5; ++i) P[i] = __builtin_amdgcn_readfirstlane(rp[nbase+i]);
  int nchE[4];
#pragma unroll
  for (int jj = 0; jj < 4; ++jj){
    int nc = (P[jj+1] - P[jj] + 7) >> 3;
    nc = (nc + 1) & ~1;
    nchE[jj] = nc < 2 ? 2 : nc;
  }
  float di0 = dinv[nbase+0], di1 = dinv[nbase+1], di2 = dinv[nbase+2], di3 = dinv[nbase+3];
  f16x2 hv0 = *(const f16x2*)(hb + (size_t)(nbase+0)*256);
  f16x2 hv1 = *(const f16x2*)(hb + (size_t)(nbase+1)*256);
  f16x2 hv2 = *(const f16x2*)(hb + (size_t)(nbase+2)*256);
  f16x2 hv3 = *(const f16x2*)(hb + (size_t)(nbase+3)*256);
  float2 bb = *(const float2*)(bias + pass*128 + lane*2);

  float wA[8], wB[8];
  f16x2 vA[8], vB[8];
  float ax0, ay0, ax1, ay1;
  float ssx = 0.f, ssy = 0.f;                  // BN partials (2 ch/lane)
  float sqx = 0.f, sqy = 0.f;

#define LOADCH(W, V, BASE, PEND) do { \
    int2 _e[8]; \
    int _b = (BASE); int _pe = (PEND); \
    _Pragma("unroll") \
    for (int _i = 0; _i < 8; ++_i){ \
      int _pc = _b + _i; \
      _pc = _pc < _pe-1 ? _pc : _pe-1; \
      _pc = _pc > 0 ? _pc : 0; \
      _e[_i] = csr_sw[_pc]; \
    } \
    _Pragma("unroll") \
    for (int _i = 0; _i < 8; ++_i){ \
      W[_i] = (_b + _i < _pe) ? __int_as_float(_e[_i].y) : 0.f; \
      V[_i] = *(const f16x2*)(hb + (size_t)_e[_i].x*256); \
    } \
  } while(0)

#define FMACH(W, V) do { \
    _Pragma("unroll") \
    for (int _i = 0; _i < 8; _i += 2){ \
      ax0 = fmaf(W[_i],   (float)V[_i][0],   ax0); \
      ay0 = fmaf(W[_i],   (float)V[_i][1],   ay0); \
      ax1 = fmaf(W[_i+1], (float)V[_i+1][0], ax1); \
      ay1 = fmaf(W[_i+1], (float)V[_i+1][1], ay1); \
    } \
  } while(0)

#define NODE(jj, DI, HV, PRE) do { \
    const int p0_ = P[jj], pend_ = P[(jj)+1]; \
    const int ncE_ = nchE[jj]; \
    float c0_ = (DI)*(DI); \
    ax0 = fmaf(c0_, (float)(HV)[0], bb.x); \
    ay0 = fmaf(c0_, (float)(HV)[1], bb.y); \
    ax1 = 0.f; ay1 = 0.f; \
    int base_ = p0_ + 8; \
    for (int k_ = 0; k_ + 2 < ncE_; k_ += 2){ \
      LOADCH(wB, vB, base_, pend_); base_ += 8; \
      FMACH(wA, vA); \
      LOADCH(wA, vA, base_, pend_); base_ += 8; \
      FMACH(wB, vB); \
    } \
    LOADCH(wB, vB, base_, pend_); \
    FMACH(wA, vA); \
    PRE; \
    FMACH(wB, vB); \
    { \
      float fx_ = ax0+ax1, fy_ = ay0+ay1; \
      *(float2*)(out + (size_t)(nbase+(jj))*256 + pass*128 + lane*2) = \
          make_float2(fx_, fy_); \
      ssx += fx_; sqx = fmaf(fx_, fx_, sqx); \
      ssy += fy_; sqy = fmaf(fy_, fy_, sqy); \
    } \
  } while(0)

  LOADCH(wA, vA, P[0], P[1]);
  NODE(0, di0, hv0, LOADCH(wA, vA, P[1], P[2]));
  NODE(1, di1, hv1, LOADCH(wA, vA, P[2], P[3]));
  NODE(2, di2, hv2, LOADCH(wA, vA, P[3], P[4]));
  NODE(3, di3, hv3, (void)0);
#undef LOADCH
#undef FMACH
#undef NODE

  // block-level BN stat reduction: 4 waves x 64 lanes x (2 s + 2 s2) -> 128 channels
  __shared__ float red[4][64][4];
  int wid = threadIdx.x >> 6;
  red[wid][lane][0] = ssx; red[wid][lane][1] = ssy;
  red[wid][lane][2] = sqx; red[wid][lane][3] = sqy;
  __syncthreads();
  int c = threadIdx.x;              // block-local channel 0..127 (threads 128+ idle)
  if (c < 128){
    float s = 0.f, s2 = 0.f;
#pragma unroll
    for (int w = 0; w < 4; ++w){
      s  += red[w][c>>1][c&1];
      s2 += red[w][c>>1][2 + (c&1)];
    }
    int sh = blockIdx.x & (NSHADOW-1);
    atomicAdd(&stats[sh*512 + pass*128 + c], s);
    atomicAdd(&stats[sh*512 + 256 + pass*128 + c], s2);
  }
}

// ---------------- conv1 SpMM: 128 ch over fp16 x, emits bf16 hi/lo split ----------------
__global__ __launch_bounds__(256) void spmm_x16(const f16* __restrict__ h,
    const int* __restrict__ rp, const int2* __restrict__ csr_sw,
    const float* __restrict__ dinv,
    ushort_t* __restrict__ ohi, ushort_t* __restrict__ olo, int n){
  int nbase = __builtin_amdgcn_readfirstlane(blockIdx.x*16 + (threadIdx.x >> 6)*4);
  if (nbase >= n) return;
  int lane = threadIdx.x & 63;
  const f16* hb = h + lane*2;

  int P[5];
#pragma unroll
  for (int i = 0; i < 5; ++i) P[i] = __builtin_amdgcn_readfirstlane(rp[nbase+i]);
  int nchE[4];
#pragma unroll
  for (int jj = 0; jj < 4; ++jj){
    int nc = (P[jj+1] - P[jj] + 7) >> 3;
    nc = (nc + 1) & ~1;
    nchE[jj] = nc < 2 ? 2 : nc;
  }
  float di0 = dinv[nbase+0], di1 = dinv[nbase+1], di2 = dinv[nbase+2], di3 = dinv[nbase+3];
  f16x2 hv0 = *(const f16x2*)(hb + (size_t)(nbase+0)*128);
  f16x2 hv1 = *(const f16x2*)(hb + (size_t)(nbase+1)*128);
  f16x2 hv2 = *(const f16x2*)(hb + (size_t)(nbase+2)*128);
  f16x2 hv3 = *(const f16x2*)(hb + (size_t)(nbase+3)*128);

  float wA[8], wB[8];
  f16x2 vA[8], vB[8];
  float ax0, ay0, ax1, ay1;

#define LOADCH(W, V, BASE, PEND) do { \
    int2 _e[8]; \
    int _b = (BASE); int _pe = (PEND); \
    _Pragma("unroll") \
    for (int _i = 0; _i < 8; ++_i){ \
      int _pc = _b + _i; \
      _pc = _pc < _pe-1 ? _pc : _pe-1; \
      _pc = _pc > 0 ? _pc : 0; \
      _e[_i] = csr_sw[_pc]; \
    } \
    _Pragma("unroll") \
    for (int _i = 0; _i < 8; ++_i){ \
      W[_i] = (_b + _i < _pe) ? __int_as_float(_e[_i].y) : 0.f; \
      V[_i] = *(const f16x2*)(hb + (size_t)_e[_i].x*128); \
    } \
  } while(0)

#define FMACH(W, V) do { \
    _Pragma("unroll") \
    for (int _i = 0; _i < 8; _i += 2){ \
      ax0 = fmaf(W[_i],   (float)V[_i][0],   ax0); \
      ay0 = fmaf(W[_i],   (float)V[_i][1],   ay0); \
      ax1 = fmaf(W[_i+1], (float)V[_i+1][0], ax1); \
      ay1 = fmaf(W[_i+1], (float)V[_i+1][1], ay1); \
    } \
  } while(0)

#define NODE(jj, DI, HV, PRE) do { \
    const int p0_ = P[jj], pend_ = P[(jj)+1]; \
    const int ncE_ = nchE[jj]; \
    float c0_ = (DI)*(DI); \
    ax0 = c0_ * (float)(HV)[0]; \
    ay0 = c0_ * (float)(HV)[1]; \
    ax1 = 0.f; ay1 = 0.f; \
    int base_ = p0_ + 8; \
    for (int k_ = 0; k_ + 2 < ncE_; k_ += 2){ \
      LOADCH(wB, vB, base_, pend_); base_ += 8; \
      FMACH(wA, vA); \
      LOADCH(wA, vA, base_, pend_); base_ += 8; \
      FMACH(wB, vB); \
    } \
    LOADCH(wB, vB, base_, pend_); \
    FMACH(wA, vA); \
    PRE; \
    FMACH(wB, vB); \
    { \
      float ax_ = ax0 + ax1, ay_ = ay0 + ay1; \
      ushort_t hx_, lx_, hy_, ly_; \
      split2(ax_, hx_, lx_); \
      split2(ay_, hy_, ly_); \
      size_t o_ = (size_t)(nbase+(jj))*128 + lane*2; \
      ohi[o_] = hx_; ohi[o_+1] = hy_; \
      olo[o_] = lx_; olo[o_+1] = ly_; \
    } \
  } while(0)

  LOADCH(wA, vA, P[0], P[1]);
  NODE(0, di0, hv0, LOADCH(wA, vA, P[1], P[2]));
  NODE(1, di1, hv1, LOADCH(wA, vA, P[2], P[3]));
  NODE(2, di2, hv2, LOADCH(wA, vA, P[3], P[4]));
  NODE(3, di3, hv3, (void)0);
#undef LOADCH
#undef FMACH
#undef NODE
}

// ---------------- BatchNorm (stats from producers; apply fused into consumer GEMM) ----------------
__global__ void zero_stats(float* __restrict__ stats){
  stats[blockIdx.x*256 + threadIdx.x] = 0.f;   // grid 128 x 256 = NSHADOW*512 (SC/SH untouched)
}

__global__ void bn_final(float* __restrict__ stats, const float* __restrict__ g,
                         const float* __restrict__ be, int n){
  int c = threadIdx.x;
  float s = 0.f, s2 = 0.f;
  for (int k = 0; k < NSHADOW; ++k){
    s  += stats[k*512 + c];
    s2 += stats[k*512 + 256 + c];
  }
  float inv_n = 1.0f / (float)n;
  float mean = s * inv_n;
  float var  = fmaxf(s2 * inv_n - mean*mean, 0.f);
  float sc   = g[c] * rsqrtf(var + EPS_BN);
  stats[STATS_SC_OFF + c] = sc;
  stats[STATS_SH_OFF + c] = be[c] - mean * sc;
}

// W[K][M] fp32 -> transposed split WtHi/WtLo[M][K] bf16
__global__ void wsplit(const float* __restrict__ W, ushort_t* __restrict__ hiT,
                       ushort_t* __restrict__ loT, int K, int M){
  int i = blockIdx.x*256 + threadIdx.x;
  if (i >= K*M) return;
  int k = i / M, m = i % M;
  ushort_t h, l;
  split2(W[i], h, l);
  hiT[(size_t)m*K + k] = h;
  loT[(size_t)m*K + k] = l;
}

// ---------------- bf16x3 split MFMA GEMM ----------------
// C[n,M] = A[n,K] @ (Bhi+Blo)^T  with B stored transposed [M][K].
// r12: big GEMMs at BM=256/16-wave (1024 threads, grid 391, all co-resident,
// 2 blocks/CU = 32 waves/CU). 2x MFMA per barrier pair vs r11's BM=128.
// Template is wave-count-generic: NW = (BM/WM)*(BN/WN), NT = NW*64.
// ACT: 0 none ; 1 bias+leaky ; 2 bias.
// OMODE: 0 fp32->Cf ; 1 split bf16->Chi/Clo ; 2 fp16->Ch
// STATS: 1 -> accumulate per-column BN (sum,sumsq) into shadow-banked stats_g.
// AMODE: 0 -> A pre-split hi/lo bf16 via async gload16.
//        1 -> A is fp32; BN scale/shift (from stats_g SC/SH) + leaky + hi/lo split
//             applied in registers during staging.
template<int BM, int BN, int WM, int WN, int ACT, int OMODE, int STATS, int AMODE>
__global__ __launch_bounds__((BM/WM)*(BN/WN)*64) void gemm_mfma(
    const ushort_t* __restrict__ Ahi_g, const ushort_t* __restrict__ Alo_g,
    const float* __restrict__ Af_g,
    const ushort_t* __restrict__ Bhi_g, const ushort_t* __restrict__ Blo_g,
    const float* __restrict__ bias,
    float* __restrict__ Cf, ushort_t* __restrict__ Chi, ushort_t* __restrict__ Clo,
    f16* __restrict__ Ch, float* __restrict__ stats_g,
    int nrows, int K, int M){
  constexpr int FI = WM/16, FJ = WN/16;
  constexpr int WCOLS = BN/WN;
  constexpr int NW = (BM/WM)*(BN/WN);   // waves per block
  constexpr int NT = NW*64;             // threads per block
  __shared__ ushort_t sAhi[BM*32];
  __shared__ ushort_t sAlo[BM*32];
  __shared__ ushort_t sBhi[BN*32];
  __shared__ ushort_t sBlo[BN*32];
  __shared__ float sSC[AMODE ? 256 : 1];
  __shared__ float sSH[AMODE ? 256 : 1];
  const int tid  = threadIdx.x;
  const int wave = tid >> 6;
  const int lane = tid & 63;
  const int r0 = blockIdx.x * BM;
  const int c0 = blockIdx.y * BN;
  const int wr0 = (wave / WCOLS) * WM;
  const int wc0 = (wave % WCOLS) * WN;
  const int m = lane & 15, q = lane >> 4;

  if constexpr (AMODE == 1){
    if (tid < K){
      sSC[tid] = stats_g[STATS_SC_OFF + tid];
      sSH[tid] = stats_g[STATS_SH_OFF + tid];
    }
    __syncthreads();
  }

  v4f acc[FI][FJ];
#pragma unroll
  for (int i = 0; i < FI; ++i)
#pragma unroll
    for (int j = 0; j < FJ; ++j) acc[i][j] = (v4f){0.f,0.f,0.f,0.f};

  const int srow = lane >> 2;                        // row within 16-row chunk
  const int kqlog = (lane & 3) ^ ((srow >> 1) & 3);  // swizzled logical 16B chunk
  const int fsw = (q ^ ((m >> 1) & 3)) * 8;          // frag read: swizzled k elem offset

  for (int kt = 0; kt < K; kt += 32){
    if constexpr (AMODE == 0){
#pragma unroll
      for (int cc = wave; cc < BM/16; cc += NW){     // A: BM/16 16-row chunks over NW waves
        int gr = r0 + cc*16 + srow;
        gr = min(gr, nrows - 1);
        size_t go = (size_t)gr*K + kt + kqlog*8;
        gload16(Ahi_g + go, &sAhi[cc*512]);
        gload16(Alo_g + go, &sAlo[cc*512]);
      }
    } else {
      // reg-staged: fp32 -> BN scale/shift -> leaky -> hi/lo split -> swizzled LDS.
#pragma unroll
      for (int pidx = tid; pidx < BM*4; pidx += NT){
        int row  = pidx >> 2;                        // 0..BM-1
        int kq   = pidx & 3;
        int gr   = min(r0 + row, nrows - 1);
        int ch0  = kt + kq*8;
        const float* ap = Af_g + (size_t)gr*K + ch0;
        float4 a0 = *(const float4*)ap;
        float4 a1 = *(const float4*)(ap + 4);
        float4 sc0 = *(const float4*)&sSC[ch0];
        float4 sc1 = *(const float4*)&sSC[ch0 + 4];
        float4 sh0 = *(const float4*)&sSH[ch0];
        float4 sh1 = *(const float4*)&sSH[ch0 + 4];
        float va[8] = {a0.x, a0.y, a0.z, a0.w, a1.x, a1.y, a1.z, a1.w};
        float vc[8] = {sc0.x, sc0.y, sc0.z, sc0.w, sc1.x, sc1.y, sc1.z, sc1.w};
        float vh[8] = {sh0.x, sh0.y, sh0.z, sh0.w, sh1.x, sh1.y, sh1.z, sh1.w};
        us8 hi8, lo8;
#pragma unroll
        for (int j = 0; j < 8; ++j){
          float v = lk(fmaf(va[j], vc[j], vh[j]));
          ushort_t hh, ll;
          split2(v, hh, ll);
          hi8[j] = hh; lo8[j] = ll;
        }
        int off = row*32 + (kq ^ ((row >> 1) & 3))*8;
        *(us8*)&sAhi[off] = hi8;
        *(us8*)&sAlo[off] = lo8;
      }
    }
    for (int cc = wave; cc < BN/16; cc += NW){
      int gr = c0 + cc*16 + srow;
      size_t go = (size_t)gr*K + kt + kqlog*8;
      gload16(Bhi_g + go, &sBhi[cc*512]);
      gload16(Blo_g + go, &sBlo[cc*512]);
    }
    __syncthreads();   // drains vmcnt (global_load_lds) per barrier semantics

    v8s ah[FI], al[FI], bh[FJ], bl[FJ];
#pragma unroll
    for (int i = 0; i < FI; ++i){
      int off = (wr0 + i*16 + m)*32 + fsw;
      ah[i] = *(const v8s*)&sAhi[off];
      al[i] = *(const v8s*)&sAlo[off];
    }
#pragma unroll
    for (int j = 0; j < FJ; ++j){
      int off = (wc0 + j*16 + m)*32 + fsw;
      bh[j] = *(const v8s*)&sBhi[off];
      bl[j] = *(const v8s*)&sBlo[off];
    }
#pragma unroll
    for (int i = 0; i < FI; ++i)
#pragma unroll
      for (int j = 0; j < FJ; ++j){
        acc[i][j] = __builtin_amdgcn_mfma_f32_16x16x32_bf16(ah[i], bh[j], acc[i][j], 0, 0, 0);
        acc[i][j] = __builtin_amdgcn_mfma_f32_16x16x32_bf16(ah[i], bl[j], acc[i][j], 0, 0, 0);
        acc[i][j] = __builtin_amdgcn_mfma_f32_16x16x32_bf16(al[i], bh[j], acc[i][j], 0, 0, 0);
      }
    __syncthreads();
  }

  // epilogue: C/D layout col = lane&15, row = (lane>>4)*4 + reg  [m89/m91]
  __shared__ float cst[STATS ? 2*BN : 1];
  if constexpr (STATS){
    for (int t = tid; t < 2*BN; t += NT) cst[t] = 0.f;
    __syncthreads();
  }
  float stj[FJ], stq[FJ];
#pragma unroll
  for (int j = 0; j < FJ; ++j){ stj[j] = 0.f; stq[j] = 0.f; }

#pragma unroll
  for (int i = 0; i < FI; ++i){
#pragma unroll
    for (int j = 0; j < FJ; ++j){
      int col = c0 + wc0 + j*16 + m;
      float bv = (ACT >= 1) ? bias[col] : 0.f;
#pragma unroll
      for (int r = 0; r < 4; ++r){
        int row = r0 + wr0 + i*16 + q*4 + r;
        if (row >= nrows) continue;
        float v = acc[i][j][r] + bv;
        if (ACT == 1) v = lk(v);
        if constexpr (STATS){
          stj[j] += v;
          stq[j] = fmaf(v, v, stq[j]);
        }
        size_t o = (size_t)row*M + col;
        if (OMODE == 1){
          ushort_t h, l; split2(v, h, l);
          Chi[o] = h; Clo[o] = l;
        } else if (OMODE == 2){
          Ch[o] = (f16)v;
        } else {
          Cf[o] = v;
        }
      }
    }
  }

  if constexpr (STATS){
#pragma unroll
    for (int j = 0; j < FJ; ++j){
      int cl = wc0 + j*16 + m;       // block-local col
      atomicAdd(&cst[cl*2 + 0], stj[j]);
      atomicAdd(&cst[cl*2 + 1], stq[j]);
    }
    __syncthreads();
    for (int t = tid; t < BN; t += NT){
      int sh = (blockIdx.x + blockIdx.y) & (NSHADOW-1);
      atomicAdd(&stats_g[sh*512 + c0 + t],        cst[t*2 + 0]);
      atomicAdd(&stats_g[sh*512 + 256 + c0 + t],  cst[t*2 + 1]);
    }
  }
}

// ---------------- launch ----------------
extern "C" void kernel_launch(void* const* d_in, const int* in_sizes, int n_in,
                              void* d_out, int out_size, void* d_ws, size_t ws_size,
                              hipStream_t stream){
  const float* x   = (const float*)d_in[0];
  const int*   ei  = (const int*)  d_in[1];
  const float* ew  = (const float*)d_in[2];
  const float* W1  = (const float*)d_in[3];
  const float* b1  = (const float*)d_in[4];
  const float* g1  = (const float*)d_in[5];
  const float* be1 = (const float*)d_in[6];
  const float* W2  = (const float*)d_in[7];
  const float* b2  = (const float*)d_in[8];
  const float* g2  = (const float*)d_in[9];
  const float* be2 = (const float*)d_in[10];
  const float* W3  = (const float*)d_in[11];
  const float* b3  = (const float*)d_in[12];
  const float* g3  = (const float*)d_in[13];
  const float* be3 = (const float*)d_in[14];
  const float* Wl1 = (const float*)d_in[15];
  const float* bl1 = (const float*)d_in[16];
  const float* Wl2 = (const float*)d_in[17];
  const float* bl2 = (const float*)d_in[18];
  const int* src = ei;
  const int* dst = ei + NE;

  // ---- workspace: 2-slot rotation + in-slot aliases ----
  char* p = (char*)d_ws;
  auto carve = [&](size_t bytes)->void*{
    void* r = (void*)p;
    p += (bytes + 255) & ~(size_t)255;
    return r;
  };
  float*    dinv    = (float*)   carve((size_t)NN*4);
  int*      rp      = (int*)     carve((size_t)(NN+1)*4);
  int*      cnt     = (int*)     carve((size_t)NN*4);
  int*      bsum    = (int*)     carve(256*4);
  float*    stats   = (float*)   carve((size_t)(NSHADOW*512 + 512)*4);   // 132 KB
  u64*      acc64   = (u64*)     carve((size_t)NN*8);
  int2*     csr_sw  = (int2*)    carve((size_t)NE*8);
  float*    S1      = (float*)   carve((size_t)NN*256*4);   // 102.4 MB slot
  float*    S2      = (float*)   carve((size_t)NN*256*4);   // 102.4 MB slot
  ushort_t* W1tH    = (ushort_t*)carve(128*256*2);
  ushort_t* W1tL    = (ushort_t*)carve(128*256*2);
  ushort_t* W2tH    = (ushort_t*)carve(256*256*2);
  ushort_t* W2tL    = (ushort_t*)carve(256*256*2);
  ushort_t* W3tH    = (ushort_t*)carve(256*256*2);
  ushort_t* W3tL    = (ushort_t*)carve(256*256*2);
  ushort_t* Wl1tH   = (ushort_t*)carve(256*256*2);
  ushort_t* Wl1tL   = (ushort_t*)carve(256*256*2);
  ushort_t* Wl2tH   = (ushort_t*)carve(256*32*2);
  ushort_t* Wl2tL   = (ushort_t*)carve(256*32*2);

  // aliased views (stream-order makes each safe):
  ushort_t* S1h256 = (ushort_t*)S1;  ushort_t* S1l256 = S1h256 + (size_t)NN*256;
  ushort_t* S1h128 = (ushort_t*)S1;  ushort_t* S1l128 = S1h128 + (size_t)NN*128;
  ushort_t* rank   = (ushort_t*)S2;       // 3.2 MB, consumed by fill_csr before cvt_x writes S2
  f16*      x16    = (f16*)S2;            // 25.6 MB, dead once spmm_x16 done
  f16*      H2f16  = (f16*)S1;            // conv2 gemm out (over dead split128), 51.2 MB
  f16*      H3f16  = (f16*)S1;            // conv3 gemm out (over dead H2), 51.2 MB

  const int nb = (NN + 1023) / 1024;
  const dim3 spmm_grid((NN + 15) / 16, 2);   // x: 16 nodes/block ; y: channel half
  const int spmm_blocks = (NN + 15) / 16;    // spmm_x16 (single pass)
  const int gemm_blocks = (NN + 255) / 256;  // BM=256, BN=256, 16 waves, single col pass

  // graph preprocessing (shared by all 3 conv layers)
  zero_acc<<<(NN+255)/256, 256, 0, stream>>>(acc64, NN);
  edge_hist<<<(NE+255)/256, 256, 0, stream>>>(dst, ew, acc64, rank, NE);
  finalize_acc<<<(NN+255)/256, 256, 0, stream>>>(acc64, dinv, cnt, NN);
  scan_block<<<nb, 1024, 0, stream>>>(cnt, rp, bsum, NN);
  scan_small<<<1, 128, 0, stream>>>(bsum, nb);
  scan_add<<<nb, 1024, 0, stream>>>(rp, bsum, NN, NE);
  fill_csr_k<<<(NE+255)/256, 256, 0, stream>>>(src, dst, ew, dinv, rp, rank, csr_sw, NE);

  // weight splits
  wsplit<<<(128*256+255)/256, 256, 0, stream>>>(W1,  W1tH,  W1tL,  128, 256);
  wsplit<<<(256*256+255)/256, 256, 0, stream>>>(W2,  W2tH,  W2tL,  256, 256);
  wsplit<<<(256*256+255)/256, 256, 0, stream>>>(W3,  W3tH,  W3tL,  256, 256);
  wsplit<<<(256*256+255)/256, 256, 0, stream>>>(Wl1, Wl1tH, Wl1tL, 256, 256);
  wsplit<<<(256*32 +255)/256, 256, 0, stream>>>(Wl2, Wl2tH, Wl2tL, 256, 32);

  dim3 gridOut((NN+127)/128, 1);

  // conv1: x->fp16 ; spmm gather -> split128 in S1 ; gemm+b1+STATS -> S2 fp32 ; bn_final
  cvt_x<<<(NN*32+255)/256, 256, 0, stream>>>(x, x16, NN*32);
  spmm_x16<<<spmm_blocks, 256, 0, stream>>>(x16, rp, csr_sw, dinv, S1h128, S1l128, NN);
  zero_stats<<<128, 256, 0, stream>>>(stats);
  gemm_mfma<256,256,64,64,2,0,1,0><<<gemm_blocks, 1024, 0, stream>>>(
      S1h128, S1l128, nullptr, W1tH, W1tL, b1, S2, nullptr, nullptr, nullptr, stats, NN, 128, 256);
  bn_final<<<1, 256, 0, stream>>>(stats, g1, be1, NN);

  // conv2: gemm reads S2 fp32 (BN1+leaky fused in staging) -> fp16 H2 in S1 ;
  //        spmm16(2-pass)+STATS S1 -> S2 fp32 ; bn_final
  zero_stats<<<128, 256, 0, stream>>>(stats);
  gemm_mfma<256,256,64,64,0,2,0,1><<<gemm_blocks, 1024, 0, stream>>>(
      nullptr, nullptr, S2, W2tH, W2tL, nullptr, nullptr, nullptr, nullptr, H2f16, stats, NN, 256, 256);
  spmm16<<<spmm_grid, 256, 0, stream>>>(H2f16, rp, csr_sw, dinv, b2, S2, stats, NN);
  bn_final<<<1, 256, 0, stream>>>(stats, g2, be2, NN);

  // conv3: gemm reads S2 fp32 (BN2+leaky fused) -> fp16 H3 in S1 ;
  //        spmm16(2-pass)+STATS S1 -> S2 fp32 ; bn_final
  zero_stats<<<128, 256, 0, stream>>>(stats);
  gemm_mfma<256,256,64,64,0,2,0,1><<<gemm_blocks, 1024, 0, stream>>>(
      nullptr, nullptr, S2, W3tH, W3tL, nullptr, nullptr, nullptr, nullptr, H3f16, stats, NN, 256, 256);
  spmm16<<<spmm_grid, 256, 0, stream>>>(H3f16, rp, csr_sw, dinv, b3, S2, stats, NN);
  bn_final<<<1, 256, 0, stream>>>(stats, g3, be3, NN);

  // head: Wl1 gemm reads S2 fp32 (BN3+leaky fused), +bl1+leaky -> S1 split ;
  //       Wl2 gemm S1 split -> d_out
  gemm_mfma<256,256,64,64,1,1,0,1><<<gemm_blocks, 1024, 0, stream>>>(
      nullptr, nullptr, S2, Wl1tH, Wl1tL, bl1, nullptr, S1h256, S1l256, nullptr, stats, NN, 256, 256);
  gemm_mfma<128,32,32,32,2,0,0,0><<<gridOut, 256, 0, stream>>>(
      S1h256, S1l256, nullptr, Wl2tH, Wl2tL, bl2, (float*)d_out, nullptr, nullptr, nullptr, nullptr, NN, 256, 32);
}

// Round 13
// 886.698 us; speedup vs baseline: 1.0632x; 1.0632x over previous
//
#include <hip/hip_runtime.h>

#define NN 100000
#define NE 1600000
#define EPS_BN 1e-5f
#define NSHADOW 64
#define STATS_SC_OFF (NSHADOW*512)
#define STATS_SH_OFF (NSHADOW*512 + 256)

typedef unsigned short ushort_t;
typedef unsigned long long u64;
typedef _Float16 f16;
typedef short v8s __attribute__((ext_vector_type(8)));     // 8 bf16 (4 VGPR)
typedef ushort_t us8 __attribute__((ext_vector_type(8)));  // 8 bf16 as ushort
typedef float v4f __attribute__((ext_vector_type(4)));     // 4 fp32 acc
typedef f16 f16x2 __attribute__((ext_vector_type(2)));
typedef f16 f16x4 __attribute__((ext_vector_type(4)));

__device__ __forceinline__ float lk(float x){ return x >= 0.f ? x : 0.1f*x; }

__device__ __forceinline__ ushort_t f2bf(float x){
  unsigned u = __float_as_uint(x);
  unsigned r = (u + 0x7fffu + ((u >> 16) & 1u)) >> 16;
  return (ushort_t)r;
}
__device__ __forceinline__ float bf2f(ushort_t h){
  return __uint_as_float(((unsigned)h) << 16);
}
__device__ __forceinline__ void split2(float x, ushort_t& hi, ushort_t& lo){
  hi = f2bf(x);
  lo = f2bf(x - bf2f(hi));
}

// async 16B global->LDS (lds dst is wave-uniform base; HW adds lane*16)
__device__ __forceinline__ void gload16(const ushort_t* g, ushort_t* l){
  __builtin_amdgcn_global_load_lds((const __attribute__((address_space(1))) void*)g,
                                   (__attribute__((address_space(3))) void*)l, 16, 0, 0);
}

// ---------------- degree+count histogram: ONE packed u64 atomic per edge ----------------
__global__ void zero_acc(u64* __restrict__ acc, int n){
  int i = blockIdx.x*256 + threadIdx.x;
  if (i < n) acc[i] = 0ull;
}

__global__ void edge_hist(const int* __restrict__ dst, const float* __restrict__ ew,
                          u64* __restrict__ acc, ushort_t* __restrict__ rank, int e){
  int i = blockIdx.x*256 + threadIdx.x;
  if (i < e){
    int d = dst[i];
    unsigned fx = (unsigned)(ew[i] * 67108864.0f + 0.5f);   // 2^26 fixed point
    u64 old = atomicAdd(&acc[d], (1ull << 40) | (u64)fx);
    rank[i] = (ushort_t)(old >> 40);                        // in-bucket rank
  }
}

__global__ void finalize_acc(const u64* __restrict__ acc, float* __restrict__ dinv,
                             int* __restrict__ cnt, int n){
  int i = blockIdx.x*256 + threadIdx.x;
  if (i < n){
    u64 v = acc[i];
    cnt[i] = (int)(v >> 40);
    double w = (double)(v & 0xFFFFFFFFFFull) * (1.0/67108864.0);
    dinv[i] = rsqrtf((float)(1.0 + w));   // +1 self loop
  }
}

// ---------------- exclusive scan (3-kernel) ----------------
__global__ __launch_bounds__(1024) void scan_block(const int* __restrict__ in, int* __restrict__ out,
                                                   int* __restrict__ bsum, int n){
  __shared__ int s[1024];
  int t = threadIdx.x;
  int i = blockIdx.x*1024 + t;
  int v = (i < n) ? in[i] : 0;
  s[t] = v; __syncthreads();
  for (int off = 1; off < 1024; off <<= 1){
    int x = (t >= off) ? s[t-off] : 0;
    __syncthreads();
    s[t] += x;
    __syncthreads();
  }
  if (i < n) out[i] = s[t] - v;
  if (t == 1023) bsum[blockIdx.x] = s[1023];
}

__global__ void scan_small(int* __restrict__ bsum, int nb){
  __shared__ int s[128];
  int t = threadIdx.x;
  int v = (t < nb) ? bsum[t] : 0;
  s[t] = v; __syncthreads();
  for (int off = 1; off < 128; off <<= 1){
    int x = (t >= off) ? s[t-off] : 0;
    __syncthreads();
    s[t] += x;
    __syncthreads();
  }
  if (t < nb) bsum[t] = s[t] - v;
}

__global__ __launch_bounds__(1024) void scan_add(int* __restrict__ rp,
                                                 const int* __restrict__ bsum, int n, int etot){
  int i = blockIdx.x*1024 + threadIdx.x;
  if (i < n) rp[i] += bsum[blockIdx.x];
  if (i == 0) rp[n] = etot;
}

// ---------------- CSR fill: atomic-free (pos = rp[d] + rank), one 8B scatter/edge ----------------
__global__ void fill_csr_k(const int* __restrict__ src, const int* __restrict__ dst,
                           const float* __restrict__ ew, const float* __restrict__ dinv,
                           const int* __restrict__ rp, const ushort_t* __restrict__ rank,
                           int2* __restrict__ csr_sw, int e){
  int i = blockIdx.x*256 + threadIdx.x;
  if (i >= e) return;
  int s = src[i], d = dst[i];
  int pos = rp[d] + (int)rank[i];
  float w = dinv[s] * ew[i] * dinv[d];
  csr_sw[pos] = make_int2(s, __float_as_int(w));
}

// ---------------- x fp32 -> fp16 convert ----------------
__global__ void cvt_x(const float* __restrict__ in, f16* __restrict__ out, int n4){
  int i = blockIdx.x*256 + threadIdx.x;
  if (i >= n4) return;
  float4 v = ((const float4*)in)[i];
  f16x4 h = (f16x4){(f16)v.x, (f16)v.y, (f16)v.z, (f16)v.w};
  ((f16x4*)out)[i] = h;
}

// ---------------- SpMM (256 ch total), channel-split into 2 passes of 128 ch ----------------
// 4 nodes per wave, continuous gather pipeline; BN stats fused (per-pass 128 ch).
// Settled at its access-pattern floor (~129 us) in r2/r6 — do not touch.
__global__ __launch_bounds__(256) void spmm16(const f16* __restrict__ h,
    const int* __restrict__ rp, const int2* __restrict__ csr_sw,
    const float* __restrict__ dinv, const float* __restrict__ bias,
    float* __restrict__ out, float* __restrict__ stats, int n){
  const int pass = blockIdx.y;                 // 0: ch 0..127 ; 1: ch 128..255
  int nbase = __builtin_amdgcn_readfirstlane(blockIdx.x*16 + (threadIdx.x >> 6)*4);
  if (nbase >= n) return;
  int lane = threadIdx.x & 63;
  const f16* hb = h + pass*128 + lane*2;       // 2 fp16 channels per lane

  int P[5];
#pragma unroll
  for (int i = 0; i < 5; ++i) P[i] = __builtin_amdgcn_readfirstlane(rp[nbase+i]);
  int nchE[4];
#pragma unroll
  for (int jj = 0; jj < 4; ++jj){
    int nc = (P[jj+1] - P[jj] + 7) >> 3;
    nc = (nc + 1) & ~1;
    nchE[jj] = nc < 2 ? 2 : nc;
  }
  float di0 = dinv[nbase+0], di1 = dinv[nbase+1], di2 = dinv[nbase+2], di3 = dinv[nbase+3];
  f16x2 hv0 = *(const f16x2*)(hb + (size_t)(nbase+0)*256);
  f16x2 hv1 = *(const f16x2*)(hb + (size_t)(nbase+1)*256);
  f16x2 hv2 = *(const f16x2*)(hb + (size_t)(nbase+2)*256);
  f16x2 hv3 = *(const f16x2*)(hb + (size_t)(nbase+3)*256);
  float2 bb = *(const float2*)(bias + pass*128 + lane*2);

  float wA[8], wB[8];
  f16x2 vA[8], vB[8];
  float ax0, ay0, ax1, ay1;
  float ssx = 0.f, ssy = 0.f;                  // BN partials (2 ch/lane)
  float sqx = 0.f, sqy = 0.f;

#define LOADCH(W, V, BASE, PEND) do { \
    int2 _e[8]; \
    int _b = (BASE); int _pe = (PEND); \
    _Pragma("unroll") \
    for (int _i = 0; _i < 8; ++_i){ \
      int _pc = _b + _i; \
      _pc = _pc < _pe-1 ? _pc : _pe-1; \
      _pc = _pc > 0 ? _pc : 0; \
      _e[_i] = csr_sw[_pc]; \
    } \
    _Pragma("unroll") \
    for (int _i = 0; _i < 8; ++_i){ \
      W[_i] = (_b + _i < _pe) ? __int_as_float(_e[_i].y) : 0.f; \
      V[_i] = *(const f16x2*)(hb + (size_t)_e[_i].x*256); \
    } \
  } while(0)

#define FMACH(W, V) do { \
    _Pragma("unroll") \
    for (int _i = 0; _i < 8; _i += 2){ \
      ax0 = fmaf(W[_i],   (float)V[_i][0],   ax0); \
      ay0 = fmaf(W[_i],   (float)V[_i][1],   ay0); \
      ax1 = fmaf(W[_i+1], (float)V[_i+1][0], ax1); \
      ay1 = fmaf(W[_i+1], (float)V[_i+1][1], ay1); \
    } \
  } while(0)

#define NODE(jj, DI, HV, PRE) do { \
    const int p0_ = P[jj], pend_ = P[(jj)+1]; \
    const int ncE_ = nchE[jj]; \
    float c0_ = (DI)*(DI); \
    ax0 = fmaf(c0_, (float)(HV)[0], bb.x); \
    ay0 = fmaf(c0_, (float)(HV)[1], bb.y); \
    ax1 = 0.f; ay1 = 0.f; \
    int base_ = p0_ + 8; \
    for (int k_ = 0; k_ + 2 < ncE_; k_ += 2){ \
      LOADCH(wB, vB, base_, pend_); base_ += 8; \
      FMACH(wA, vA); \
      LOADCH(wA, vA, base_, pend_); base_ += 8; \
      FMACH(wB, vB); \
    } \
    LOADCH(wB, vB, base_, pend_); \
    FMACH(wA, vA); \
    PRE; \
    FMACH(wB, vB); \
    { \
      float fx_ = ax0+ax1, fy_ = ay0+ay1; \
      *(float2*)(out + (size_t)(nbase+(jj))*256 + pass*128 + lane*2) = \
          make_float2(fx_, fy_); \
      ssx += fx_; sqx = fmaf(fx_, fx_, sqx); \
      ssy += fy_; sqy = fmaf(fy_, fy_, sqy); \
    } \
  } while(0)

  LOADCH(wA, vA, P[0], P[1]);
  NODE(0, di0, hv0, LOADCH(wA, vA, P[1], P[2]));
  NODE(1, di1, hv1, LOADCH(wA, vA, P[2], P[3]));
  NODE(2, di2, hv2, LOADCH(wA, vA, P[3], P[4]));
  NODE(3, di3, hv3, (void)0);
#undef LOADCH
#undef FMACH
#undef NODE

  // block-level BN stat reduction: 4 waves x 64 lanes x (2 s + 2 s2) -> 128 channels
  __shared__ float red[4][64][4];
  int wid = threadIdx.x >> 6;
  red[wid][lane][0] = ssx; red[wid][lane][1] = ssy;
  red[wid][lane][2] = sqx; red[wid][lane][3] = sqy;
  __syncthreads();
  int c = threadIdx.x;              // block-local channel 0..127 (threads 128+ idle)
  if (c < 128){
    float s = 0.f, s2 = 0.f;
#pragma unroll
    for (int w = 0; w < 4; ++w){
      s  += red[w][c>>1][c&1];
      s2 += red[w][c>>1][2 + (c&1)];
    }
    int sh = blockIdx.x & (NSHADOW-1);
    atomicAdd(&stats[sh*512 + pass*128 + c], s);
    atomicAdd(&stats[sh*512 + 256 + pass*128 + c], s2);
  }
}

// ---------------- conv1 SpMM: 128 ch over fp16 x, emits bf16 hi/lo split ----------------
__global__ __launch_bounds__(256) void spmm_x16(const f16* __restrict__ h,
    const int* __restrict__ rp, const int2* __restrict__ csr_sw,
    const float* __restrict__ dinv,
    ushort_t* __restrict__ ohi, ushort_t* __restrict__ olo, int n){
  int nbase = __builtin_amdgcn_readfirstlane(blockIdx.x*16 + (threadIdx.x >> 6)*4);
  if (nbase >= n) return;
  int lane = threadIdx.x & 63;
  const f16* hb = h + lane*2;

  int P[5];
#pragma unroll
  for (int i = 0; i < 5; ++i) P[i] = __builtin_amdgcn_readfirstlane(rp[nbase+i]);
  int nchE[4];
#pragma unroll
  for (int jj = 0; jj < 4; ++jj){
    int nc = (P[jj+1] - P[jj] + 7) >> 3;
    nc = (nc + 1) & ~1;
    nchE[jj] = nc < 2 ? 2 : nc;
  }
  float di0 = dinv[nbase+0], di1 = dinv[nbase+1], di2 = dinv[nbase+2], di3 = dinv[nbase+3];
  f16x2 hv0 = *(const f16x2*)(hb + (size_t)(nbase+0)*128);
  f16x2 hv1 = *(const f16x2*)(hb + (size_t)(nbase+1)*128);
  f16x2 hv2 = *(const f16x2*)(hb + (size_t)(nbase+2)*128);
  f16x2 hv3 = *(const f16x2*)(hb + (size_t)(nbase+3)*128);

  float wA[8], wB[8];
  f16x2 vA[8], vB[8];
  float ax0, ay0, ax1, ay1;

#define LOADCH(W, V, BASE, PEND) do { \
    int2 _e[8]; \
    int _b = (BASE); int _pe = (PEND); \
    _Pragma("unroll") \
    for (int _i = 0; _i < 8; ++_i){ \
      int _pc = _b + _i; \
      _pc = _pc < _pe-1 ? _pc : _pe-1; \
      _pc = _pc > 0 ? _pc : 0; \
      _e[_i] = csr_sw[_pc]; \
    } \
    _Pragma("unroll") \
    for (int _i = 0; _i < 8; ++_i){ \
      W[_i] = (_b + _i < _pe) ? __int_as_float(_e[_i].y) : 0.f; \
      V[_i] = *(const f16x2*)(hb + (size_t)_e[_i].x*128); \
    } \
  } while(0)

#define FMACH(W, V) do { \
    _Pragma("unroll") \
    for (int _i = 0; _i < 8; _i += 2){ \
      ax0 = fmaf(W[_i],   (float)V[_i][0],   ax0); \
      ay0 = fmaf(W[_i],   (float)V[_i][1],   ay0); \
      ax1 = fmaf(W[_i+1], (float)V[_i+1][0], ax1); \
      ay1 = fmaf(W[_i+1], (float)V[_i+1][1], ay1); \
    } \
  } while(0)

#define NODE(jj, DI, HV, PRE) do { \
    const int p0_ = P[jj], pend_ = P[(jj)+1]; \
    const int ncE_ = nchE[jj]; \
    float c0_ = (DI)*(DI); \
    ax0 = c0_ * (float)(HV)[0]; \
    ay0 = c0_ * (float)(HV)[1]; \
    ax1 = 0.f; ay1 = 0.f; \
    int base_ = p0_ + 8; \
    for (int k_ = 0; k_ + 2 < ncE_; k_ += 2){ \
      LOADCH(wB, vB, base_, pend_); base_ += 8; \
      FMACH(wA, vA); \
      LOADCH(wA, vA, base_, pend_); base_ += 8; \
      FMACH(wB, vB); \
    } \
    LOADCH(wB, vB, base_, pend_); \
    FMACH(wA, vA); \
    PRE; \
    FMACH(wB, vB); \
    { \
      float ax_ = ax0 + ax1, ay_ = ay0 + ay1; \
      ushort_t hx_, lx_, hy_, ly_; \
      split2(ax_, hx_, lx_); \
      split2(ay_, hy_, ly_); \
      size_t o_ = (size_t)(nbase+(jj))*128 + lane*2; \
      ohi[o_] = hx_; ohi[o_+1] = hy_; \
      olo[o_] = lx_; olo[o_+1] = ly_; \
    } \
  } while(0)

  LOADCH(wA, vA, P[0], P[1]);
  NODE(0, di0, hv0, LOADCH(wA, vA, P[1], P[2]));
  NODE(1, di1, hv1, LOADCH(wA, vA, P[2], P[3]));
  NODE(2, di2, hv2, LOADCH(wA, vA, P[3], P[4]));
  NODE(3, di3, hv3, (void)0);
#undef LOADCH
#undef FMACH
#undef NODE
}

// ---------------- BatchNorm (stats from producers; apply fused into consumer GEMM) ----------------
__global__ void zero_stats(float* __restrict__ stats){
  stats[blockIdx.x*256 + threadIdx.x] = 0.f;   // grid 128 x 256 = NSHADOW*512 (SC/SH untouched)
}

__global__ void bn_final(float* __restrict__ stats, const float* __restrict__ g,
                         const float* __restrict__ be, int n){
  int c = threadIdx.x;
  float s = 0.f, s2 = 0.f;
  for (int k = 0; k < NSHADOW; ++k){
    s  += stats[k*512 + c];
    s2 += stats[k*512 + 256 + c];
  }
  float inv_n = 1.0f / (float)n;
  float mean = s * inv_n;
  float var  = fmaxf(s2 * inv_n - mean*mean, 0.f);
  float sc   = g[c] * rsqrtf(var + EPS_BN);
  stats[STATS_SC_OFF + c] = sc;
  stats[STATS_SH_OFF + c] = be[c] - mean * sc;
}

// W[K][M] fp32 -> transposed split WtHi/WtLo[M][K] bf16
__global__ void wsplit(const float* __restrict__ W, ushort_t* __restrict__ hiT,
                       ushort_t* __restrict__ loT, int K, int M){
  int i = blockIdx.x*256 + threadIdx.x;
  if (i >= K*M) return;
  int k = i / M, m = i % M;
  ushort_t h, l;
  split2(W[i], h, l);
  hiT[(size_t)m*K + k] = h;
  loT[(size_t)m*K + k] = l;
}

// ---------------- bf16x3 split MFMA GEMM ----------------
// C[n,M] = A[n,K] @ (Bhi+Blo)^T  with B stored transposed [M][K].
// r13 = r11 revert: big GEMMs at BM=128/8-wave (512 threads) — the bracketed
// tile optimum (BM=64: 923 us total, BM=128: 892, BM=256: ~920).
// Template is wave-count-generic: NW = (BM/WM)*(BN/WN), NT = NW*64.
// ACT: 0 none ; 1 bias+leaky ; 2 bias.
// OMODE: 0 fp32->Cf ; 1 split bf16->Chi/Clo ; 2 fp16->Ch
// STATS: 1 -> accumulate per-column BN (sum,sumsq) into shadow-banked stats_g.
// AMODE: 0 -> A pre-split hi/lo bf16 via async gload16.
//        1 -> A is fp32; BN scale/shift (from stats_g SC/SH) + leaky + hi/lo split
//             applied in registers during staging.
template<int BM, int BN, int WM, int WN, int ACT, int OMODE, int STATS, int AMODE>
__global__ __launch_bounds__((BM/WM)*(BN/WN)*64) void gemm_mfma(
    const ushort_t* __restrict__ Ahi_g, const ushort_t* __restrict__ Alo_g,
    const float* __restrict__ Af_g,
    const ushort_t* __restrict__ Bhi_g, const ushort_t* __restrict__ Blo_g,
    const float* __restrict__ bias,
    float* __restrict__ Cf, ushort_t* __restrict__ Chi, ushort_t* __restrict__ Clo,
    f16* __restrict__ Ch, float* __restrict__ stats_g,
    int nrows, int K, int M){
  constexpr int FI = WM/16, FJ = WN/16;
  constexpr int WCOLS = BN/WN;
  constexpr int NW = (BM/WM)*(BN/WN);   // waves per block
  constexpr int NT = NW*64;             // threads per block
  __shared__ ushort_t sAhi[BM*32];
  __shared__ ushort_t sAlo[BM*32];
  __shared__ ushort_t sBhi[BN*32];
  __shared__ ushort_t sBlo[BN*32];
  __shared__ float sSC[AMODE ? 256 : 1];
  __shared__ float sSH[AMODE ? 256 : 1];
  const int tid  = threadIdx.x;
  const int wave = tid >> 6;
  const int lane = tid & 63;
  const int r0 = blockIdx.x * BM;
  const int c0 = blockIdx.y * BN;
  const int wr0 = (wave / WCOLS) * WM;
  const int wc0 = (wave % WCOLS) * WN;
  const int m = lane & 15, q = lane >> 4;

  if constexpr (AMODE == 1){
    if (tid < K){
      sSC[tid] = stats_g[STATS_SC_OFF + tid];
      sSH[tid] = stats_g[STATS_SH_OFF + tid];
    }
    __syncthreads();
  }

  v4f acc[FI][FJ];
#pragma unroll
  for (int i = 0; i < FI; ++i)
#pragma unroll
    for (int j = 0; j < FJ; ++j) acc[i][j] = (v4f){0.f,0.f,0.f,0.f};

  const int srow = lane >> 2;                        // row within 16-row chunk
  const int kqlog = (lane & 3) ^ ((srow >> 1) & 3);  // swizzled logical 16B chunk
  const int fsw = (q ^ ((m >> 1) & 3)) * 8;          // frag read: swizzled k elem offset

  for (int kt = 0; kt < K; kt += 32){
    if constexpr (AMODE == 0){
#pragma unroll
      for (int cc = wave; cc < BM/16; cc += NW){     // A: BM/16 16-row chunks over NW waves
        int gr = r0 + cc*16 + srow;
        gr = min(gr, nrows - 1);
        size_t go = (size_t)gr*K + kt + kqlog*8;
        gload16(Ahi_g + go, &sAhi[cc*512]);
        gload16(Alo_g + go, &sAlo[cc*512]);
      }
    } else {
      // reg-staged: fp32 -> BN scale/shift -> leaky -> hi/lo split -> swizzled LDS.
#pragma unroll
      for (int pidx = tid; pidx < BM*4; pidx += NT){
        int row  = pidx >> 2;                        // 0..BM-1
        int kq   = pidx & 3;
        int gr   = min(r0 + row, nrows - 1);
        int ch0  = kt + kq*8;
        const float* ap = Af_g + (size_t)gr*K + ch0;
        float4 a0 = *(const float4*)ap;
        float4 a1 = *(const float4*)(ap + 4);
        float4 sc0 = *(const float4*)&sSC[ch0];
        float4 sc1 = *(const float4*)&sSC[ch0 + 4];
        float4 sh0 = *(const float4*)&sSH[ch0];
        float4 sh1 = *(const float4*)&sSH[ch0 + 4];
        float va[8] = {a0.x, a0.y, a0.z, a0.w, a1.x, a1.y, a1.z, a1.w};
        float vc[8] = {sc0.x, sc0.y, sc0.z, sc0.w, sc1.x, sc1.y, sc1.z, sc1.w};
        float vh[8] = {sh0.x, sh0.y, sh0.z, sh0.w, sh1.x, sh1.y, sh1.z, sh1.w};
        us8 hi8, lo8;
#pragma unroll
        for (int j = 0; j < 8; ++j){
          float v = lk(fmaf(va[j], vc[j], vh[j]));
          ushort_t hh, ll;
          split2(v, hh, ll);
          hi8[j] = hh; lo8[j] = ll;
        }
        int off = row*32 + (kq ^ ((row >> 1) & 3))*8;
        *(us8*)&sAhi[off] = hi8;
        *(us8*)&sAlo[off] = lo8;
      }
    }
    for (int cc = wave; cc < BN/16; cc += NW){
      int gr = c0 + cc*16 + srow;
      size_t go = (size_t)gr*K + kt + kqlog*8;
      gload16(Bhi_g + go, &sBhi[cc*512]);
      gload16(Blo_g + go, &sBlo[cc*512]);
    }
    __syncthreads();   // drains vmcnt (global_load_lds) per barrier semantics

    v8s ah[FI], al[FI], bh[FJ], bl[FJ];
#pragma unroll
    for (int i = 0; i < FI; ++i){
      int off = (wr0 + i*16 + m)*32 + fsw;
      ah[i] = *(const v8s*)&sAhi[off];
      al[i] = *(const v8s*)&sAlo[off];
    }
#pragma unroll
    for (int j = 0; j < FJ; ++j){
      int off = (wc0 + j*16 + m)*32 + fsw;
      bh[j] = *(const v8s*)&sBhi[off];
      bl[j] = *(const v8s*)&sBlo[off];
    }
#pragma unroll
    for (int i = 0; i < FI; ++i)
#pragma unroll
      for (int j = 0; j < FJ; ++j){
        acc[i][j] = __builtin_amdgcn_mfma_f32_16x16x32_bf16(ah[i], bh[j], acc[i][j], 0, 0, 0);
        acc[i][j] = __builtin_amdgcn_mfma_f32_16x16x32_bf16(ah[i], bl[j], acc[i][j], 0, 0, 0);
        acc[i][j] = __builtin_amdgcn_mfma_f32_16x16x32_bf16(al[i], bh[j], acc[i][j], 0, 0, 0);
      }
    __syncthreads();
  }

  // epilogue: C/D layout col = lane&15, row = (lane>>4)*4 + reg  [m89/m91]
  __shared__ float cst[STATS ? 2*BN : 1];
  if constexpr (STATS){
    for (int t = tid; t < 2*BN; t += NT) cst[t] = 0.f;
    __syncthreads();
  }
  float stj[FJ], stq[FJ];
#pragma unroll
  for (int j = 0; j < FJ; ++j){ stj[j] = 0.f; stq[j] = 0.f; }

#pragma unroll
  for (int i = 0; i < FI; ++i){
#pragma unroll
    for (int j = 0; j < FJ; ++j){
      int col = c0 + wc0 + j*16 + m;
      float bv = (ACT >= 1) ? bias[col] : 0.f;
#pragma unroll
      for (int r = 0; r < 4; ++r){
        int row = r0 + wr0 + i*16 + q*4 + r;
        if (row >= nrows) continue;
        float v = acc[i][j][r] + bv;
        if (ACT == 1) v = lk(v);
        if constexpr (STATS){
          stj[j] += v;
          stq[j] = fmaf(v, v, stq[j]);
        }
        size_t o = (size_t)row*M + col;
        if (OMODE == 1){
          ushort_t h, l; split2(v, h, l);
          Chi[o] = h; Clo[o] = l;
        } else if (OMODE == 2){
          Ch[o] = (f16)v;
        } else {
          Cf[o] = v;
        }
      }
    }
  }

  if constexpr (STATS){
#pragma unroll
    for (int j = 0; j < FJ; ++j){
      int cl = wc0 + j*16 + m;       // block-local col
      atomicAdd(&cst[cl*2 + 0], stj[j]);
      atomicAdd(&cst[cl*2 + 1], stq[j]);
    }
    __syncthreads();
    for (int t = tid; t < BN; t += NT){
      int sh = (blockIdx.x + blockIdx.y) & (NSHADOW-1);
      atomicAdd(&stats_g[sh*512 + c0 + t],        cst[t*2 + 0]);
      atomicAdd(&stats_g[sh*512 + 256 + c0 + t],  cst[t*2 + 1]);
    }
  }
}

// ---------------- launch ----------------
extern "C" void kernel_launch(void* const* d_in, const int* in_sizes, int n_in,
                              void* d_out, int out_size, void* d_ws, size_t ws_size,
                              hipStream_t stream){
  const float* x   = (const float*)d_in[0];
  const int*   ei  = (const int*)  d_in[1];
  const float* ew  = (const float*)d_in[2];
  const float* W1  = (const float*)d_in[3];
  const float* b1  = (const float*)d_in[4];
  const float* g1  = (const float*)d_in[5];
  const float* be1 = (const float*)d_in[6];
  const float* W2  = (const float*)d_in[7];
  const float* b2  = (const float*)d_in[8];
  const float* g2  = (const float*)d_in[9];
  const float* be2 = (const float*)d_in[10];
  const float* W3  = (const float*)d_in[11];
  const float* b3  = (const float*)d_in[12];
  const float* g3  = (const float*)d_in[13];
  const float* be3 = (const float*)d_in[14];
  const float* Wl1 = (const float*)d_in[15];
  const float* bl1 = (const float*)d_in[16];
  const float* Wl2 = (const float*)d_in[17];
  const float* bl2 = (const float*)d_in[18];
  const int* src = ei;
  const int* dst = ei + NE;

  // ---- workspace: 2-slot rotation + in-slot aliases ----
  char* p = (char*)d_ws;
  auto carve = [&](size_t bytes)->void*{
    void* r = (void*)p;
    p += (bytes + 255) & ~(size_t)255;
    return r;
  };
  float*    dinv    = (float*)   carve((size_t)NN*4);
  int*      rp      = (int*)     carve((size_t)(NN+1)*4);
  int*      cnt     = (int*)     carve((size_t)NN*4);
  int*      bsum    = (int*)     carve(256*4);
  float*    stats   = (float*)   carve((size_t)(NSHADOW*512 + 512)*4);   // 132 KB
  u64*      acc64   = (u64*)     carve((size_t)NN*8);
  int2*     csr_sw  = (int2*)    carve((size_t)NE*8);
  float*    S1      = (float*)   carve((size_t)NN*256*4);   // 102.4 MB slot
  float*    S2      = (float*)   carve((size_t)NN*256*4);   // 102.4 MB slot
  ushort_t* W1tH    = (ushort_t*)carve(128*256*2);
  ushort_t* W1tL    = (ushort_t*)carve(128*256*2);
  ushort_t* W2tH    = (ushort_t*)carve(256*256*2);
  ushort_t* W2tL    = (ushort_t*)carve(256*256*2);
  ushort_t* W3tH    = (ushort_t*)carve(256*256*2);
  ushort_t* W3tL    = (ushort_t*)carve(256*256*2);
  ushort_t* Wl1tH   = (ushort_t*)carve(256*256*2);
  ushort_t* Wl1tL   = (ushort_t*)carve(256*256*2);
  ushort_t* Wl2tH   = (ushort_t*)carve(256*32*2);
  ushort_t* Wl2tL   = (ushort_t*)carve(256*32*2);

  // aliased views (stream-order makes each safe):
  ushort_t* S1h256 = (ushort_t*)S1;  ushort_t* S1l256 = S1h256 + (size_t)NN*256;
  ushort_t* S1h128 = (ushort_t*)S1;  ushort_t* S1l128 = S1h128 + (size_t)NN*128;
  ushort_t* rank   = (ushort_t*)S2;       // 3.2 MB, consumed by fill_csr before cvt_x writes S2
  f16*      x16    = (f16*)S2;            // 25.6 MB, dead once spmm_x16 done
  f16*      H2f16  = (f16*)S1;            // conv2 gemm out (over dead split128), 51.2 MB
  f16*      H3f16  = (f16*)S1;            // conv3 gemm out (over dead H2), 51.2 MB

  const int nb = (NN + 1023) / 1024;
  const dim3 spmm_grid((NN + 15) / 16, 2);   // x: 16 nodes/block ; y: channel half
  const int spmm_blocks = (NN + 15) / 16;    // spmm_x16 (single pass)
  const int gemm_blocks = (NN + 127) / 128;  // BM=128, BN=256, single column pass, 8 waves

  // graph preprocessing (shared by all 3 conv layers)
  zero_acc<<<(NN+255)/256, 256, 0, stream>>>(acc64, NN);
  edge_hist<<<(NE+255)/256, 256, 0, stream>>>(dst, ew, acc64, rank, NE);
  finalize_acc<<<(NN+255)/256, 256, 0, stream>>>(acc64, dinv, cnt, NN);
  scan_block<<<nb, 1024, 0, stream>>>(cnt, rp, bsum, NN);
  scan_small<<<1, 128, 0, stream>>>(bsum, nb);
  scan_add<<<nb, 1024, 0, stream>>>(rp, bsum, NN, NE);
  fill_csr_k<<<(NE+255)/256, 256, 0, stream>>>(src, dst, ew, dinv, rp, rank, csr_sw, NE);

  // weight splits
  wsplit<<<(128*256+255)/256, 256, 0, stream>>>(W1,  W1tH,  W1tL,  128, 256);
  wsplit<<<(256*256+255)/256, 256, 0, stream>>>(W2,  W2tH,  W2tL,  256, 256);
  wsplit<<<(256*256+255)/256, 256, 0, stream>>>(W3,  W3tH,  W3tL,  256, 256);
  wsplit<<<(256*256+255)/256, 256, 0, stream>>>(Wl1, Wl1tH, Wl1tL, 256, 256);
  wsplit<<<(256*32 +255)/256, 256, 0, stream>>>(Wl2, Wl2tH, Wl2tL, 256, 32);

  dim3 gridOut((NN+127)/128, 1);

  // conv1: x->fp16 ; spmm gather -> split128 in S1 ; gemm+b1+STATS -> S2 fp32 ; bn_final
  cvt_x<<<(NN*32+255)/256, 256, 0, stream>>>(x, x16, NN*32);
  spmm_x16<<<spmm_blocks, 256, 0, stream>>>(x16, rp, csr_sw, dinv, S1h128, S1l128, NN);
  zero_stats<<<128, 256, 0, stream>>>(stats);
  gemm_mfma<128,256,64,64,2,0,1,0><<<gemm_blocks, 512, 0, stream>>>(
      S1h128, S1l128, nullptr, W1tH, W1tL, b1, S2, nullptr, nullptr, nullptr, stats, NN, 128, 256);
  bn_final<<<1, 256, 0, stream>>>(stats, g1, be1, NN);

  // conv2: gemm reads S2 fp32 (BN1+leaky fused in staging) -> fp16 H2 in S1 ;
  //        spmm16(2-pass)+STATS S1 -> S2 fp32 ; bn_final
  zero_stats<<<128, 256, 0, stream>>>(stats);
  gemm_mfma<128,256,64,64,0,2,0,1><<<gemm_blocks, 512, 0, stream>>>(
      nullptr, nullptr, S2, W2tH, W2tL, nullptr, nullptr, nullptr, nullptr, H2f16, stats, NN, 256, 256);
  spmm16<<<spmm_grid, 256, 0, stream>>>(H2f16, rp, csr_sw, dinv, b2, S2, stats, NN);
  bn_final<<<1, 256, 0, stream>>>(stats, g2, be2, NN);

  // conv3: gemm reads S2 fp32 (BN2+leaky fused) -> fp16 H3 in S1 ;
  //        spmm16(2-pass)+STATS S1 -> S2 fp32 ; bn_final
  zero_stats<<<128, 256, 0, stream>>>(stats);
  gemm_mfma<128,256,64,64,0,2,0,1><<<gemm_blocks, 512, 0, stream>>>(
      nullptr, nullptr, S2, W3tH, W3tL, nullptr, nullptr, nullptr, nullptr, H3f16, stats, NN, 256, 256);
  spmm16<<<spmm_grid, 256, 0, stream>>>(H3f16, rp, csr_sw, dinv, b3, S2, stats, NN);
  bn_final<<<1, 256, 0, stream>>>(stats, g3, be3, NN);

  // head: Wl1 gemm reads S2 fp32 (BN3+leaky fused), +bl1+leaky -> S1 split ;
  //       Wl2 gemm S1 split -> d_out
  gemm_mfma<128,256,64,64,1,1,0,1><<<gemm_blocks, 512, 0, stream>>>(
      nullptr, nullptr, S2, Wl1tH, Wl1tL, bl1, nullptr, S1h256, S1l256, nullptr, stats, NN, 256, 256);
  gemm_mfma<128,32,32,32,2,0,0,0><<<gridOut, 256, 0, stream>>>(
      S1h256, S1l256, nullptr, Wl2tH, Wl2tL, bl2, (float*)d_out, nullptr, nullptr, nullptr, nullptr, NN, 256, 32);
}